// Round 1
// baseline (37.859 us; speedup 1.0000x reference)
//
#include <hip/hip_runtime.h>

// Problem constants (match reference)
static constexpr int CB = 2;
static constexpr int CN = 256;
static constexpr int CK = 16;
#define F_ALPHA 0.01f
#define F_LAM   1.0f
#define F_KAPPA 1.0f
#define F_EPS   1e-6f
#define F_GCLIP 1000.0f

// ---------------------------------------------------------------------------
// Kernel 1: per (b,n) compute
//   R  = expm(sum_a phi[b,n,a] * G[a])        (K x K, orthogonal)
//   u  = R^T mu_q[b,n]                        (K)
//   W  = (R^T diag(max(sigma_q,eps)) R + eps I)^{-1}   (K x K, SPD)
// One block of 256 threads per (b,n); thread t owns matrix element (t/16, t%16).
// expm via scaling (1/16) + 12-term Taylor + 4 squarings.
// ---------------------------------------------------------------------------
__global__ __launch_bounds__(256) void vfe_prep_kernel(
    const float* __restrict__ mu_q, const float* __restrict__ sigma_q,
    const float* __restrict__ phi, const float* __restrict__ gens,
    float* __restrict__ wsR, float* __restrict__ wsW, float* __restrict__ wsU)
{
    const int bn = blockIdx.x;          // 0 .. B*N-1
    const int t  = threadIdx.x;         // 0 .. 255
    const int r  = t >> 4;
    const int c  = t & 15;

    __shared__ float Ms[256];   // scaled generator combination
    __shared__ float P[256];    // Taylor power term
    __shared__ float T[256];    // accumulated expm
    __shared__ float Ssh[256];  // S matrix for inversion
    __shared__ float Ish[256];  // inverse (starts as I)
    __shared__ float msh[CK];
    __shared__ float sgsh[CK];

    const float p0 = phi[bn*3+0];
    const float p1 = phi[bn*3+1];
    const float p2 = phi[bn*3+2];

    const float diag = (r == c) ? 1.0f : 0.0f;
    // M = sum_a phi_a * G_a   , scaled by 1/16 (4 squarings later)
    float m = p0*gens[t] + p1*gens[256+t] + p2*gens[512+t];
    Ms[t] = m * (1.0f/16.0f);
    __syncthreads();

    // Taylor: T = I + X + X^2/2! + ... + X^12/12!
    P[t] = Ms[t];
    T[t] = diag + Ms[t];
    for (int k = 2; k <= 12; ++k) {
        __syncthreads();
        float acc = 0.f;
        #pragma unroll
        for (int l = 0; l < CK; ++l) acc += P[r*CK+l] * Ms[l*CK+c];
        acc *= (1.0f / (float)k);
        __syncthreads();
        P[t] = acc;
        T[t] += acc;
    }
    // square 4 times: T <- T*T
    for (int sq = 0; sq < 4; ++sq) {
        __syncthreads();
        float acc = 0.f;
        #pragma unroll
        for (int l = 0; l < CK; ++l) acc += T[r*CK+l] * T[l*CK+c];
        __syncthreads();
        T[t] = acc;
    }
    __syncthreads();

    // write R
    wsR[bn*256 + t] = T[t];

    // stage mu, clipped sigma
    if (t < CK) {
        msh[t]  = mu_q[bn*CK + t];
        sgsh[t] = fmaxf(sigma_q[bn*CK + t], F_EPS);
    }
    __syncthreads();

    // u = R^T mu  (threads 0..15, component t)
    if (t < CK) {
        float acc = 0.f;
        #pragma unroll
        for (int l = 0; l < CK; ++l) acc += T[l*CK+t] * msh[l];
        wsU[bn*CK + t] = acc;
    }

    // S = R^T diag(sg) R + eps*I
    {
        float acc = 0.f;
        #pragma unroll
        for (int l = 0; l < CK; ++l) acc += T[l*CK+r] * sgsh[l] * T[l*CK+c];
        if (r == c) acc += F_EPS;
        Ssh[t] = acc;
        Ish[t] = diag;
    }

    // Gauss-Jordan inverse (SPD, no pivoting needed; cond <= ~10)
    for (int k = 0; k < CK; ++k) {
        __syncthreads();
        const float rp = 1.0f / Ssh[k*CK+k];
        __syncthreads();
        if (r == k) { Ssh[t] *= rp; Ish[t] *= rp; }
        __syncthreads();
        const float f   = Ssh[r*CK+k];
        const float pr  = Ssh[k*CK+c];
        const float pir = Ish[k*CK+c];
        __syncthreads();
        if (r != k) { Ssh[t] -= f*pr; Ish[t] -= f*pir; }
    }
    __syncthreads();
    wsW[bn*256 + t] = Ish[t];
}

// ---------------------------------------------------------------------------
// Kernel 2: per (b,i) accumulate over j (one thread per j), then epilogue.
//   d   = u_i - u_j
//   h   = W_j d           (rotated-frame g)
//   kl  = 0.5 d.h
//   s1 += beta*h ; s2 += beta*kl*h ; s3 += beta*kl
//   grad_rot = LAM*s1 + (LAM/KAPPA)*(s2 - s3*s1);  grad = R_i @ grad_rot
// ---------------------------------------------------------------------------
__global__ __launch_bounds__(256) void vfe_pair_kernel(
    const float* __restrict__ mu_q, const float* __restrict__ sigma_q,
    const float* __restrict__ mu_p, const float* __restrict__ sigma_p,
    const float* __restrict__ beta, const float* __restrict__ lr,
    const float* __restrict__ wsR, const float* __restrict__ wsW,
    const float* __restrict__ wsU, float* __restrict__ out)
{
    const int bi = blockIdx.x;      // b*N + i
    const int b  = bi >> 8;         // N = 256
    const int i  = bi & 255;
    const int j  = threadIdx.x;     // 0..255

    __shared__ float uish[CK];
    __shared__ float part[4][33];
    __shared__ float red[33];
    __shared__ float grot[CK];

    if (j < CK) uish[j] = wsU[bi*CK + j];
    __syncthreads();

    // d = u_i - u_j
    const float4* uj4 = (const float4*)(wsU + (b*CN + j)*CK);
    float d[CK];
    #pragma unroll
    for (int q = 0; q < 4; ++q) {
        const float4 a = uj4[q];
        d[4*q+0] = uish[4*q+0] - a.x;
        d[4*q+1] = uish[4*q+1] - a.y;
        d[4*q+2] = uish[4*q+2] - a.z;
        d[4*q+3] = uish[4*q+3] - a.w;
    }

    // h = W_j d ; kl = 0.5 d.h
    const float4* W4 = (const float4*)(wsW + (b*CN + j)*256);
    float h[CK];
    float kl = 0.f;
    #pragma unroll
    for (int rr = 0; rr < CK; ++rr) {
        float acc = 0.f;
        #pragma unroll
        for (int q = 0; q < 4; ++q) {
            const float4 w = W4[rr*4+q];
            acc += w.x*d[4*q+0] + w.y*d[4*q+1] + w.z*d[4*q+2] + w.w*d[4*q+3];
        }
        h[rr] = acc;
        kl += acc * d[rr];
    }
    kl *= 0.5f;

    const float bt  = beta[(b*CN + i)*CN + j];
    const float wkl = bt * kl;

    // 33 accumulands: [0..15]=bt*h, [16..31]=wkl*h, [32]=wkl
    float v[33];
    #pragma unroll
    for (int q = 0; q < CK; ++q) { v[q] = bt*h[q]; v[16+q] = wkl*h[q]; }
    v[32] = wkl;

    // wave64 reduction then cross-wave via LDS
    #pragma unroll
    for (int q = 0; q < 33; ++q) {
        float x = v[q];
        x += __shfl_down(x, 32);
        x += __shfl_down(x, 16);
        x += __shfl_down(x, 8);
        x += __shfl_down(x, 4);
        x += __shfl_down(x, 2);
        x += __shfl_down(x, 1);
        v[q] = x;
    }
    const int lane = j & 63;
    const int wv   = j >> 6;
    if (lane == 0) {
        #pragma unroll
        for (int q = 0; q < 33; ++q) part[wv][q] = v[q];
    }
    __syncthreads();
    if (j < 33) red[j] = part[0][j] + part[1][j] + part[2][j] + part[3][j];
    __syncthreads();

    if (j < CK) {
        const float s1 = red[j];
        const float s2 = red[16+j];
        const float s3 = red[32];
        grot[j] = F_LAM*s1 + (F_LAM/F_KAPPA)*(s2 - s3*s1);
    }
    __syncthreads();

    if (j < CK) {
        const int rr = j;
        const float* Ri = wsR + bi*256;
        float acc = 0.f;
        #pragma unroll
        for (int cc = 0; cc < CK; ++cc) acc += Ri[rr*CK+cc] * grot[cc];

        const int idx = bi*CK + rr;
        const float mq = mu_q[idx];
        const float sq = sigma_q[idx];
        const float mp = mu_p[idx];
        const float sp = sigma_p[idx];
        const float sps = fmaxf(sp, F_EPS);
        const float sqs = fmaxf(sq, F_EPS);

        const float gmu = F_ALPHA*(mq - mp)/sps + acc;
        const float gsg = F_ALPHA*0.5f*(1.0f/sps - 1.0f/sqs);

        float nmu = sqs * gmu;
        float nsg = 0.5f * sqs * sqs * gsg;
        nmu = fminf(fmaxf(nmu, -F_GCLIP), F_GCLIP);
        nsg = fminf(fmaxf(nsg, -F_GCLIP), F_GCLIP);

        const float step = lr[0];
        out[idx]             = mq - step*nmu;                 // mu_new
        out[CB*CN*CK + idx]  = fmaxf(sq - step*nsg, F_EPS);   // sigma_new
    }
}

extern "C" void kernel_launch(void* const* d_in, const int* in_sizes, int n_in,
                              void* d_out, int out_size, void* d_ws, size_t ws_size,
                              hipStream_t stream) {
    const float* mu_q    = (const float*)d_in[0];
    const float* sigma_q = (const float*)d_in[1];
    const float* mu_p    = (const float*)d_in[2];
    const float* sigma_p = (const float*)d_in[3];
    const float* beta    = (const float*)d_in[4];
    const float* phi     = (const float*)d_in[5];
    const float* gens    = (const float*)d_in[6];
    const float* lr      = (const float*)d_in[7];
    float* out = (float*)d_out;

    float* wsR = (float*)d_ws;                 // B*N*K*K = 131072 floats
    float* wsW = wsR + CB*CN*CK*CK;            // B*N*K*K
    float* wsU = wsW + CB*CN*CK*CK;            // B*N*K   =   8192 floats

    vfe_prep_kernel<<<CB*CN, 256, 0, stream>>>(mu_q, sigma_q, phi, gens, wsR, wsW, wsU);
    vfe_pair_kernel<<<CB*CN, 256, 0, stream>>>(mu_q, sigma_q, mu_p, sigma_p, beta, lr,
                                               wsR, wsW, wsU, out);
}

// Round 2
// 32.866 us; speedup vs baseline: 1.1519x; 1.1519x over previous
//
#include <hip/hip_runtime.h>

// Problem constants (match reference)
static constexpr int CB = 2;
static constexpr int CN = 256;
static constexpr int CK = 16;
#define F_ALPHA 0.01f
#define F_LAM   1.0f
#define F_KAPPA 1.0f
#define F_EPS   1e-6f
#define F_GCLIP 1000.0f

// ---------------------------------------------------------------------------
// Kernel 1: per (b,n) compute
//   R  = expm(sum_a phi[b,n,a] * G[a])        (K x K, orthogonal)
//   u  = R^T mu_q[b,n]                        (K)
//   W  = R^T diag(1/(max(sigma_q,eps)+eps)) R (K x K, SPD)
// Orthogonality of R gives the exact analytic inverse:
//   (Omega D Omega^T + eps I)^{-1} = Omega (D+eps I)^{-1} Omega^T
// so NO Gauss-Jordan is needed (removes 64 barriers + serial divides).
// expm via scaling (1/16) + 8-term Taylor + 4 squarings (||M/16|| <~ 0.2,
// truncation ~3e-11).
// One block of 256 threads per (b,n); thread t owns element (t/16, t%16).
// ---------------------------------------------------------------------------
__global__ __launch_bounds__(256) void vfe_prep_kernel(
    const float* __restrict__ mu_q, const float* __restrict__ sigma_q,
    const float* __restrict__ phi, const float* __restrict__ gens,
    float* __restrict__ wsR, float* __restrict__ wsW, float* __restrict__ wsU)
{
    const int bn = blockIdx.x;          // 0 .. B*N-1
    const int t  = threadIdx.x;         // 0 .. 255
    const int r  = t >> 4;
    const int c  = t & 15;

    __shared__ float Ms[256];   // scaled generator combination
    __shared__ float P[256];    // Taylor power term
    __shared__ float T[256];    // accumulated expm
    __shared__ float msh[CK];
    __shared__ float dinv[CK];  // 1/(sigma_safe + eps)

    const float p0 = phi[bn*3+0];
    const float p1 = phi[bn*3+1];
    const float p2 = phi[bn*3+2];

    const float diag = (r == c) ? 1.0f : 0.0f;
    // M = sum_a phi_a * G_a , scaled by 1/16 (4 squarings later)
    float m = p0*gens[t] + p1*gens[256+t] + p2*gens[512+t];
    Ms[t] = m * (1.0f/16.0f);

    // stage mu, dinv while matrix work proceeds
    if (t < CK) {
        msh[t]  = mu_q[bn*CK + t];
        dinv[t] = 1.0f / (fmaxf(sigma_q[bn*CK + t], F_EPS) + F_EPS);
    }
    __syncthreads();

    // Taylor: T = I + X + X^2/2! + ... + X^8/8!
    P[t] = Ms[t];
    T[t] = diag + Ms[t];
    #pragma unroll
    for (int k = 2; k <= 8; ++k) {
        __syncthreads();
        float acc = 0.f;
        #pragma unroll
        for (int l = 0; l < CK; ++l) acc += P[r*CK+l] * Ms[l*CK+c];
        acc *= (1.0f / (float)k);
        __syncthreads();
        P[t] = acc;
        T[t] += acc;
    }
    // square 4 times: T <- T*T
    #pragma unroll
    for (int sq = 0; sq < 4; ++sq) {
        __syncthreads();
        float acc = 0.f;
        #pragma unroll
        for (int l = 0; l < CK; ++l) acc += T[r*CK+l] * T[l*CK+c];
        __syncthreads();
        T[t] = acc;
    }
    __syncthreads();

    // write R
    wsR[bn*256 + t] = T[t];

    // u = R^T mu  (threads 0..15, component t)
    if (t < CK) {
        float acc = 0.f;
        #pragma unroll
        for (int l = 0; l < CK; ++l) acc += T[l*CK+t] * msh[l];
        wsU[bn*CK + t] = acc;
    }

    // W = R^T Dinv R   (analytic inverse of R^T D R + eps I)
    {
        float acc = 0.f;
        #pragma unroll
        for (int l = 0; l < CK; ++l) acc += T[l*CK+r] * dinv[l] * T[l*CK+c];
        wsW[bn*256 + t] = acc;
    }
}

// ---------------------------------------------------------------------------
// Kernel 2: per (b,i) accumulate over j (one thread per j), then epilogue.
//   d   = u_i - u_j
//   h   = W_j d           (rotated-frame g)
//   kl  = 0.5 d.h
//   s1 += beta*h ; s2 += beta*kl*h ; s3 += beta*kl
//   grad_rot = LAM*s1 + (LAM/KAPPA)*(s2 - s3*s1);  grad = R_i @ grad_rot
// ---------------------------------------------------------------------------
__global__ __launch_bounds__(256) void vfe_pair_kernel(
    const float* __restrict__ mu_q, const float* __restrict__ sigma_q,
    const float* __restrict__ mu_p, const float* __restrict__ sigma_p,
    const float* __restrict__ beta, const float* __restrict__ lr,
    const float* __restrict__ wsR, const float* __restrict__ wsW,
    const float* __restrict__ wsU, float* __restrict__ out)
{
    const int bi = blockIdx.x;      // b*N + i
    const int b  = bi >> 8;         // N = 256
    const int i  = bi & 255;
    const int j  = threadIdx.x;     // 0..255

    __shared__ float uish[CK];
    __shared__ float part[4][33];
    __shared__ float red[33];
    __shared__ float grot[CK];

    if (j < CK) uish[j] = wsU[bi*CK + j];
    __syncthreads();

    // d = u_i - u_j
    const float4* uj4 = (const float4*)(wsU + (b*CN + j)*CK);
    float d[CK];
    #pragma unroll
    for (int q = 0; q < 4; ++q) {
        const float4 a = uj4[q];
        d[4*q+0] = uish[4*q+0] - a.x;
        d[4*q+1] = uish[4*q+1] - a.y;
        d[4*q+2] = uish[4*q+2] - a.z;
        d[4*q+3] = uish[4*q+3] - a.w;
    }

    // h = W_j d ; kl = 0.5 d.h
    const float4* W4 = (const float4*)(wsW + (b*CN + j)*256);
    float h[CK];
    float kl = 0.f;
    #pragma unroll
    for (int rr = 0; rr < CK; ++rr) {
        float acc = 0.f;
        #pragma unroll
        for (int q = 0; q < 4; ++q) {
            const float4 w = W4[rr*4+q];
            acc += w.x*d[4*q+0] + w.y*d[4*q+1] + w.z*d[4*q+2] + w.w*d[4*q+3];
        }
        h[rr] = acc;
        kl += acc * d[rr];
    }
    kl *= 0.5f;

    const float bt  = beta[(b*CN + i)*CN + j];
    const float wkl = bt * kl;

    // 33 accumulands: [0..15]=bt*h, [16..31]=wkl*h, [32]=wkl
    float v[33];
    #pragma unroll
    for (int q = 0; q < CK; ++q) { v[q] = bt*h[q]; v[16+q] = wkl*h[q]; }
    v[32] = wkl;

    // wave64 reduction then cross-wave via LDS
    #pragma unroll
    for (int q = 0; q < 33; ++q) {
        float x = v[q];
        x += __shfl_down(x, 32);
        x += __shfl_down(x, 16);
        x += __shfl_down(x, 8);
        x += __shfl_down(x, 4);
        x += __shfl_down(x, 2);
        x += __shfl_down(x, 1);
        v[q] = x;
    }
    const int lane = j & 63;
    const int wv   = j >> 6;
    if (lane == 0) {
        #pragma unroll
        for (int q = 0; q < 33; ++q) part[wv][q] = v[q];
    }
    __syncthreads();
    if (j < 33) red[j] = part[0][j] + part[1][j] + part[2][j] + part[3][j];
    __syncthreads();

    if (j < CK) {
        const float s1 = red[j];
        const float s2 = red[16+j];
        const float s3 = red[32];
        grot[j] = F_LAM*s1 + (F_LAM/F_KAPPA)*(s2 - s3*s1);
    }
    __syncthreads();

    if (j < CK) {
        const int rr = j;
        const float* Ri = wsR + bi*256;
        float acc = 0.f;
        #pragma unroll
        for (int cc = 0; cc < CK; ++cc) acc += Ri[rr*CK+cc] * grot[cc];

        const int idx = bi*CK + rr;
        const float mq = mu_q[idx];
        const float sq = sigma_q[idx];
        const float mp = mu_p[idx];
        const float sp = sigma_p[idx];
        const float sps = fmaxf(sp, F_EPS);
        const float sqs = fmaxf(sq, F_EPS);

        const float gmu = F_ALPHA*(mq - mp)/sps + acc;
        const float gsg = F_ALPHA*0.5f*(1.0f/sps - 1.0f/sqs);

        float nmu = sqs * gmu;
        float nsg = 0.5f * sqs * sqs * gsg;
        nmu = fminf(fmaxf(nmu, -F_GCLIP), F_GCLIP);
        nsg = fminf(fmaxf(nsg, -F_GCLIP), F_GCLIP);

        const float step = lr[0];
        out[idx]             = mq - step*nmu;                 // mu_new
        out[CB*CN*CK + idx]  = fmaxf(sq - step*nsg, F_EPS);   // sigma_new
    }
}

extern "C" void kernel_launch(void* const* d_in, const int* in_sizes, int n_in,
                              void* d_out, int out_size, void* d_ws, size_t ws_size,
                              hipStream_t stream) {
    const float* mu_q    = (const float*)d_in[0];
    const float* sigma_q = (const float*)d_in[1];
    const float* mu_p    = (const float*)d_in[2];
    const float* sigma_p = (const float*)d_in[3];
    const float* beta    = (const float*)d_in[4];
    const float* phi     = (const float*)d_in[5];
    const float* gens    = (const float*)d_in[6];
    const float* lr      = (const float*)d_in[7];
    float* out = (float*)d_out;

    float* wsR = (float*)d_ws;                 // B*N*K*K = 131072 floats
    float* wsW = wsR + CB*CN*CK*CK;            // B*N*K*K
    float* wsU = wsW + CB*CN*CK*CK;            // B*N*K   =   8192 floats

    vfe_prep_kernel<<<CB*CN, 256, 0, stream>>>(mu_q, sigma_q, phi, gens, wsR, wsW, wsU);
    vfe_pair_kernel<<<CB*CN, 256, 0, stream>>>(mu_q, sigma_q, mu_p, sigma_p, beta, lr,
                                               wsR, wsW, wsU, out);
}

// Round 3
// 21.274 us; speedup vs baseline: 1.7796x; 1.5448x over previous
//
#include <hip/hip_runtime.h>

// Problem constants (match reference)
static constexpr int CB = 2;
static constexpr int CN = 256;
static constexpr int CK = 16;
#define F_ALPHA 0.01f
#define F_LAM   1.0f
#define F_KAPPA 1.0f
#define F_EPS   1e-6f
#define F_GCLIP 1000.0f

// ---------------------------------------------------------------------------
// Kernel 1: per (b,n) compute
//   R  = expm(sum_a phi[b,n,a] * G[a])            (orthogonal)
//   u  = R^T mu_q[b,n]
//   W  = R^T diag(1/(max(sigma_q,eps)+eps)) R     (analytic inverse, no GJ)
// Outputs stored TRANSPOSED over n for coalesced reads in kernel 2:
//   wsWT[b][k][n]  (k = r*16+c),  wsUT[b][c][n],  wsR row-major per (b,n).
// expm: scale 1/16, 8 Taylor terms (ping-pong, 1 barrier/iter), 4 squarings.
// ---------------------------------------------------------------------------
__global__ __launch_bounds__(256) void vfe_prep_kernel(
    const float* __restrict__ mu_q, const float* __restrict__ sigma_q,
    const float* __restrict__ phi, const float* __restrict__ gens,
    float* __restrict__ wsR, float* __restrict__ wsWT, float* __restrict__ wsUT)
{
    const int bn = blockIdx.x;          // 0 .. B*N-1
    const int b  = bn >> 8;
    const int n  = bn & 255;
    const int t  = threadIdx.x;         // element (r,c)
    const int r  = t >> 4;
    const int c  = t & 15;

    __shared__ float Ms[256];
    __shared__ float Pa[256], Pb[256];
    __shared__ float Ta[256], Tb[256];
    __shared__ float msh[CK], dinv[CK];

    const float p0 = phi[bn*3+0];
    const float p1 = phi[bn*3+1];
    const float p2 = phi[bn*3+2];

    const float diag = (r == c) ? 1.0f : 0.0f;
    float m = p0*gens[t] + p1*gens[256+t] + p2*gens[512+t];
    m *= (1.0f/16.0f);                  // 4 squarings later
    Ms[t] = m;
    Pa[t] = m;
    if (t < CK) {
        msh[t]  = mu_q[bn*CK + t];
        dinv[t] = 1.0f / (fmaxf(sigma_q[bn*CK + t], F_EPS) + F_EPS);
    }
    __syncthreads();

    // cache column c of Ms in registers (reused by every Taylor iter)
    float mscol[CK];
    #pragma unroll
    for (int l = 0; l < CK; ++l) mscol[l] = Ms[l*CK + c];

    float Treg = diag + m;
    // Taylor terms k=2..8 (tail ~3e-8 worst case), ping-pong Pa/Pb
    #pragma unroll
    for (int k = 2; k <= 8; ++k) {
        const float* Pc = (k & 1) ? Pb : Pa;   // k=2 reads Pa
        float*       Pn = (k & 1) ? Pa : Pb;
        float acc = 0.f;
        #pragma unroll
        for (int l = 0; l < CK; ++l) acc += Pc[r*CK+l] * mscol[l];
        acc *= (1.0f / (float)k);
        Pn[t] = acc;
        Treg += acc;
        __syncthreads();
    }

    // 4 squarings, ping-pong Ta/Tb, 1 barrier each; final lands in Ta
    Ta[t] = Treg;
    __syncthreads();
    float fin = 0.f;
    #pragma unroll
    for (int s = 0; s < 4; ++s) {
        const float* Tc = (s & 1) ? Tb : Ta;
        float*       Tn = (s & 1) ? Ta : Tb;
        float acc = 0.f;
        #pragma unroll
        for (int l = 0; l < CK; ++l) acc += Tc[r*CK+l] * Tc[l*CK+c];
        Tn[t] = acc;
        fin = acc;
        __syncthreads();
    }

    // R row-major from register (own element)
    wsR[bn*256 + t] = fin;

    // u = R^T mu, stored transposed over n
    if (t < CK) {
        float acc = 0.f;
        #pragma unroll
        for (int l = 0; l < CK; ++l) acc += Ta[l*CK+t] * msh[l];
        wsUT[(b*CK + t)*CN + n] = acc;
    }

    // W = R^T Dinv R, element (r,c) stored at [b][k=t][n]
    {
        float acc = 0.f;
        #pragma unroll
        for (int l = 0; l < CK; ++l) acc += Ta[l*CK+r] * dinv[l] * Ta[l*CK+c];
        wsWT[(b*CN + t)*CN + n] = acc;
    }
}

// ---------------------------------------------------------------------------
// Kernel 2: per (b,i), one thread per j. All W/u reads perfectly coalesced
// (lane j reads [..][j], stride 4B across lanes).
//   d = u_i - u_j ; h = W_j d ; kl = 0.5 d.h
//   s1=Σβh ; s2=Σβ·kl·h ; s3=Σβ·kl ; grad = R_i (LAM·s1 + LAM/κ·(s2 - s3·s1))
// ---------------------------------------------------------------------------
__global__ __launch_bounds__(256) void vfe_pair_kernel(
    const float* __restrict__ mu_q, const float* __restrict__ sigma_q,
    const float* __restrict__ mu_p, const float* __restrict__ sigma_p,
    const float* __restrict__ beta, const float* __restrict__ lr,
    const float* __restrict__ wsR, const float* __restrict__ wsWT,
    const float* __restrict__ wsUT, float* __restrict__ out)
{
    const int bi = blockIdx.x;      // b*N + i
    const int b  = bi >> 8;
    const int i  = bi & 255;
    const int j  = threadIdx.x;     // 0..255

    __shared__ float uish[CK];
    __shared__ float part[4][33];
    __shared__ float red[33];
    __shared__ float grot[CK];

    if (j < CK) uish[j] = wsUT[(b*CK + j)*CN + i];
    __syncthreads();

    // d = u_i - u_j   (coalesced b32 reads)
    const float* uTb = wsUT + b*CK*CN;
    float d[CK];
    #pragma unroll
    for (int cc = 0; cc < CK; ++cc) d[cc] = uish[cc] - uTb[cc*CN + j];

    // h = W_j d ; kl = 0.5 d.h   (coalesced b32 reads, SGPR-walked base)
    const float* WTb = wsWT + (b*CN)*CN + j;
    float h[CK];
    float kl = 0.f;
    #pragma unroll
    for (int rr = 0; rr < CK; ++rr) {
        float acc = 0.f;
        #pragma unroll
        for (int cc = 0; cc < CK; ++cc) acc += WTb[(rr*CK + cc)*CN] * d[cc];
        h[rr] = acc;
        kl += acc * d[rr];
    }
    kl *= 0.5f;

    const float bt  = beta[(b*CN + i)*CN + j];
    const float wkl = bt * kl;

    // 33 accumulands: [0..15]=bt*h, [16..31]=wkl*h, [32]=wkl
    float v[33];
    #pragma unroll
    for (int q = 0; q < CK; ++q) { v[q] = bt*h[q]; v[16+q] = wkl*h[q]; }
    v[32] = wkl;

    // wave64 butterfly then cross-wave via LDS
    #pragma unroll
    for (int q = 0; q < 33; ++q) {
        float x = v[q];
        x += __shfl_down(x, 32);
        x += __shfl_down(x, 16);
        x += __shfl_down(x, 8);
        x += __shfl_down(x, 4);
        x += __shfl_down(x, 2);
        x += __shfl_down(x, 1);
        v[q] = x;
    }
    const int lane = j & 63;
    const int wv   = j >> 6;
    if (lane == 0) {
        #pragma unroll
        for (int q = 0; q < 33; ++q) part[wv][q] = v[q];
    }
    __syncthreads();
    if (j < 33) red[j] = part[0][j] + part[1][j] + part[2][j] + part[3][j];
    __syncthreads();

    if (j < CK) {
        const float s1 = red[j];
        const float s2 = red[16+j];
        const float s3 = red[32];
        grot[j] = F_LAM*s1 + (F_LAM/F_KAPPA)*(s2 - s3*s1);
    }
    __syncthreads();

    if (j < CK) {
        const int rr = j;
        const float* Ri = wsR + bi*256;
        float acc = 0.f;
        #pragma unroll
        for (int cc = 0; cc < CK; ++cc) acc += Ri[rr*CK+cc] * grot[cc];

        const int idx = bi*CK + rr;
        const float mq = mu_q[idx];
        const float sq = sigma_q[idx];
        const float mp = mu_p[idx];
        const float sp = sigma_p[idx];
        const float sps = fmaxf(sp, F_EPS);
        const float sqs = fmaxf(sq, F_EPS);

        const float gmu = F_ALPHA*(mq - mp)/sps + acc;
        const float gsg = F_ALPHA*0.5f*(1.0f/sps - 1.0f/sqs);

        float nmu = sqs * gmu;
        float nsg = 0.5f * sqs * sqs * gsg;
        nmu = fminf(fmaxf(nmu, -F_GCLIP), F_GCLIP);
        nsg = fminf(fmaxf(nsg, -F_GCLIP), F_GCLIP);

        const float step = lr[0];
        out[idx]             = mq - step*nmu;                 // mu_new
        out[CB*CN*CK + idx]  = fmaxf(sq - step*nsg, F_EPS);   // sigma_new
    }
}

extern "C" void kernel_launch(void* const* d_in, const int* in_sizes, int n_in,
                              void* d_out, int out_size, void* d_ws, size_t ws_size,
                              hipStream_t stream) {
    const float* mu_q    = (const float*)d_in[0];
    const float* sigma_q = (const float*)d_in[1];
    const float* mu_p    = (const float*)d_in[2];
    const float* sigma_p = (const float*)d_in[3];
    const float* beta    = (const float*)d_in[4];
    const float* phi     = (const float*)d_in[5];
    const float* gens    = (const float*)d_in[6];
    const float* lr      = (const float*)d_in[7];
    float* out = (float*)d_out;

    float* wsR  = (float*)d_ws;                // B*N*K*K floats (row-major per node)
    float* wsWT = wsR + CB*CN*CK*CK;           // [b][k][n]
    float* wsUT = wsWT + CB*CN*CK*CK;          // [b][c][n]

    vfe_prep_kernel<<<CB*CN, 256, 0, stream>>>(mu_q, sigma_q, phi, gens, wsR, wsWT, wsUT);
    vfe_pair_kernel<<<CB*CN, 256, 0, stream>>>(mu_q, sigma_q, mu_p, sigma_p, beta, lr,
                                               wsR, wsWT, wsUT, out);
}